// Round 1
// baseline (194.896 us; speedup 1.0000x reference)
//
#include <hip/hip_runtime.h>
#include <hip/hip_bf16.h>

// ---------------------------------------------------------------------------
// NHRepNet fused forward, Round 15: two-group software pipeline (A/B stagger).
//
// Established (R1-R14):
//  - Occupancy tiers power-of-2 (64/128/256 regs); 112 total (64 arch + 48
//    acc) -> 128-tier -> 2 blk/CU. Gate: WRITE_SIZE.
//  - Pipes at R14: LDS-B ~54us, VALU ~54us, MFMA ~35us, L2-A ~27us.
//    Counters (MfmaUtil 30 + VALUBusy 47 = 77% combined) show the two
//    dominant pipes are phase-SERIALIZED by the per-layer
//    [mfma phase | bar | valu phase | bar] structure.
//
// R15: split 96-pt tile into two 48-pt in-place groups A/B, staggered by half
// a layer. Every inter-barrier region = mfma(X, layer l) || epilogue(Y):
// independent streams on disjoint LDS buffers + disjoint accs -> scheduler
// interleaves softplus VALU under MFMA/ds_read. Same LDS (52224B), same
// barrier count (16), acc = 2 x [2][3] = 48 regs (NTG=3 dodges R12's dual-acc
// spill). Layer-3 splice is now a wave7/quad3-only runtime fixup so the layer
// loop stays rolled (small I-cache) with no per-act select on other layers.
// Tail blocks: 32 pts = two 16-pt groups (NTG=1), same schedule.
// ---------------------------------------------------------------------------

using bf16x8 = __attribute__((ext_vector_type(8))) __bf16;
using f32x4  = __attribute__((ext_vector_type(4))) float;

#define LDA 264   // padded activation row stride (bf16)

#define OFFW0 0
#define OFFW1 8192
#define OFFW7 401408
#define WSB_BYTE_OFF 811008   // fp32 bias region
#define OFFB7 1792            // L0..L6 at l*256; L7 at 1792 (16 floats, padded)

#define SCALE_T2 144.26950408889634f      // 100*log2(e)
#define INV_SQRT2 0.70710678118654752f
#define LN2_100 0.0069314718055994531f    // ln2/100

__device__ __forceinline__ float fast_exp2(float x) {
#if __has_builtin(__builtin_amdgcn_exp2f)
    return __builtin_amdgcn_exp2f(x);
#else
    return exp2f(x);
#endif
}
__device__ __forceinline__ float fast_log2(float x) {
#if __has_builtin(__builtin_amdgcn_logf)
    return __builtin_amdgcn_logf(x);
#else
    return log2f(x);
#endif
}

// a2 = max(t2,0) + log2(1 + 2^-|t2|)   (t2-domain; scales folded into weights)
__device__ __forceinline__ float softplus_t2(float t2) {
    float e = fast_exp2(-fabsf(t2));
    float l = fast_log2(1.0f + e);
    return fmaxf(t2, 0.0f) + l;
}

__device__ __forceinline__ unsigned short bf16_rne(float f) {
    unsigned int u = __float_as_uint(f);
    unsigned int r = u + 0x7FFFu + ((u >> 16) & 1u);
    return (unsigned short)(r >> 16);
}

// ---------------------------------------------------------------------------
// MFMA half of a layer for one group: read act (group base), acc = W.act + b.
// Wave owns ch strips [wave*32, wave*32+32); covers all NTG*16 group points.
// ---------------------------------------------------------------------------
template <int KK, int NTG>
__device__ __forceinline__ void mfma_group(
    const unsigned short* __restrict__ wfrag,
    const float* __restrict__ bias,
    const unsigned short* act,
    f32x4 (&acc)[2][NTG], int wave, int lane)
{
    const int quad = lane >> 4;
    const int l15  = lane & 15;

#pragma unroll
    for (int i = 0; i < 2; ++i) {
        const int chb = (wave * 2 + i) * 16 + quad * 4;
        const float4 b4 = *(const float4*)(bias + chb);
#pragma unroll
        for (int nt = 0; nt < NTG; ++nt)
            acc[i][nt] = f32x4{b4.x, b4.y, b4.z, b4.w};
    }

    const unsigned short* wbase = wfrag + (wave * 2 * KK * 64 + lane) * 8;

#pragma unroll
    for (int kk = 0; kk < KK; ++kk) {
        bf16x8 bfr[NTG];
#pragma unroll
        for (int nt = 0; nt < NTG; ++nt)
            bfr[nt] = *(const bf16x8*)(act + (nt * 16 + l15) * LDA + kk * 32 + quad * 8);
#pragma unroll
        for (int i = 0; i < 2; ++i) {
            bf16x8 afr = *(const bf16x8*)(wbase + (i * KK + kk) * 512);
#pragma unroll
            for (int nt = 0; nt < NTG; ++nt)
                acc[i][nt] = __builtin_amdgcn_mfma_f32_16x16x32_bf16(afr, bfr[nt], acc[i][nt], 0, 0, 0);
        }
    }
}

// ---------------------------------------------------------------------------
// Activation half: softplus + bf16 pack + write back to act (in-place, same
// group). splice (runtime, wave-uniform): layer-3 raw-x fixup -- only lanes
// with chb==252 (wave 7, i=1, quad=3) touch ch 253..255.
// ---------------------------------------------------------------------------
template <int NTG>
__device__ __forceinline__ void epi_group(
    f32x4 (&acc)[2][NTG], unsigned short* act, const float* xst,
    int wave, int lane, bool splice)
{
    const int quad = lane >> 4;
    const int l15  = lane & 15;

#pragma unroll
    for (int i = 0; i < 2; ++i) {
        const int chb = (wave * 2 + i) * 16 + quad * 4;
#pragma unroll
        for (int nt = 0; nt < NTG; ++nt) {
            const int pt = nt * 16 + l15;
            float vv[4];
#pragma unroll
            for (int r = 0; r < 4; ++r)
                vv[r] = softplus_t2(acc[i][nt][r]);
            if (splice && chb == 252) {   // ch 253..255 <- raw x (W4 absorbs scales)
                vv[1] = xst[pt * 4 + 0];
                vv[2] = xst[pt * 4 + 1];
                vv[3] = xst[pt * 4 + 2];
            }
            __hip_bfloat162 p01 = __float22bfloat162_rn(float2{vv[0], vv[1]});
            __hip_bfloat162 p23 = __float22bfloat162_rn(float2{vv[2], vv[3]});
            uint2 pk;
            pk.x = *(unsigned int*)&p01;
            pk.y = *(unsigned int*)&p23;
            *(uint2*)(act + pt * LDA + chb) = pk;
        }
    }
}

// ---------------------------------------------------------------------------
// Full network for one tile of 2*NTG*16 points (NTG=3 -> 96, NTG=1 -> 32),
// processed as two staggered in-place groups A (rows 0..NTG*16) and
// B (rows NTG*16..2*NTG*16). Region schedule (bar = __syncthreads):
//   stage; bar
//   R0 : mfma_A(0); bar
//   R1 : mfma_B(0) || epi_A(0); bar
//   l=1..6:  mfma_A(l) || epi_B(l-1); bar;  mfma_B(l) || epi_A(l); bar
//   R14: epi_B(6); bar
//   R15: L7 both groups (waves 0..2*NTG-1, 16 pts each)
// Every region mixes an MFMA/LDS stream with an independent VALU stream.
// ---------------------------------------------------------------------------
template <int NTG>
__device__ __forceinline__ void run_net(
    const float* __restrict__ x, float* __restrict__ out,
    const unsigned short* __restrict__ wsW, const float* __restrict__ wsB,
    unsigned short* act, float* xst,
    int base_pt, int npts, int tid)
{
    const int wave = tid >> 6, lane = tid & 63;
    const int quad = lane >> 4, l15 = lane & 15;

    // stage x into act channels 0..2, zero-pad to 32 (K-pad for layer 0)
    for (int i = tid; i < 2 * NTG * 16 * 32; i += 512) {
        const int pt = i >> 5, ch = i & 31;
        const int ptg = base_pt + pt;
        float v = 0.0f;
        if (ch < 3 && ptg < npts) v = x[ptg * 3 + ch];
        act[pt * LDA + ch] = bf16_rne(v);
        if (ch < 4) xst[pt * 4 + ch] = (ch < 3) ? v : 0.0f;
    }
    __syncthreads();

    unsigned short* actA = act;
    unsigned short* actB = act + NTG * 16 * LDA;
    const float* xstA = xst;
    const float* xstB = xst + NTG * 16 * 4;

    f32x4 accA[2][NTG], accB[2][NTG];

    // R0: layer 0 on group A alone (KK=1, tiny)
    mfma_group<1, NTG>(wsW + OFFW0, wsB, actA, accA, wave, lane);
    __syncthreads();

    // R1: layer 0 on B || activation of A(0)
    mfma_group<1, NTG>(wsW + OFFW0, wsB, actB, accB, wave, lane);
    epi_group<NTG>(accA, actA, xstA, wave, lane, false);
    __syncthreads();

    // layers 1..6, two regions each; runtime l keeps code small (I-cache)
#pragma unroll 1
    for (int l = 1; l <= 6; ++l) {
        const unsigned short* Wl = wsW + OFFW1 + (l - 1) * 65536;
        const float* bl = wsB + l * 256;

        // mfma_A(l) || epi_B(l-1)   (splice when l-1 == 3)
        mfma_group<8, NTG>(Wl, bl, actA, accA, wave, lane);
        epi_group<NTG>(accB, actB, xstB, wave, lane, l == 4);
        __syncthreads();

        // mfma_B(l) || epi_A(l)     (splice when l == 3)
        mfma_group<8, NTG>(Wl, bl, actB, accB, wave, lane);
        epi_group<NTG>(accA, actA, xstA, wave, lane, l == 3);
        __syncthreads();
    }

    // R14: last activation of group B
    epi_group<NTG>(accB, actB, xstB, wave, lane, false);
    __syncthreads();

    // R15: layer 7 (256 -> 8) for BOTH groups: waves 0..2*NTG-1, 16 pts each.
    // Group rows are contiguous, so row base = wave*16 spans A then B.
    if (wave < 2 * NTG) {
        const float4 b4 = *(const float4*)(wsB + OFFB7 + quad * 4);  // quads>=2: zeros
        f32x4 acc = f32x4{b4.x, b4.y, b4.z, b4.w};
        const unsigned short* w7 = wsW + OFFW7;
#pragma unroll
        for (int kk = 0; kk < 8; ++kk) {
            bf16x8 bfr = *(const bf16x8*)(act + (wave * 16 + l15) * LDA + kk * 32 + quad * 8);
            bf16x8 afr = *(const bf16x8*)(w7 + (kk * 64 + lane) * 8);
            acc = __builtin_amdgcn_mfma_f32_16x16x32_bf16(afr, bfr, acc, 0, 0, 0);
        }
        // quad0 lanes hold ch0-3, quad1 ch4-7 for pt = wave*16+l15
        float u0 = __shfl(acc[0], l15 + 16);
        float u1 = __shfl(acc[1], l15 + 16);
        float u2 = __shfl(acc[2], l15 + 16);
        float u3 = __shfl(acc[3], l15 + 16);
        if (quad == 0) {
            const int ptg = base_pt + wave * 16 + l15;
            if (ptg < npts) {
                const float v0 = acc[0], v1 = acc[1], v2 = acc[2], v3 = acc[3];
                const float v4 = u0, v5 = u1, v6 = u2, v7 = u3;
                const float m23   = fminf(v2, v3);
                const float m67   = fmaxf(v6, v7);
                const float m4567 = fminf(fminf(v4, v5), m67);
                const float h     = fmaxf(fmaxf(v0, v1), fmaxf(m23, m4567));
                float* o = out + (long)ptg * 9;
                o[0] = h;
                o[1] = v0; o[2] = v1; o[3] = v2; o[4] = v3;
                o[5] = v4; o[6] = v5; o[7] = v6; o[8] = v7;
            }
        }
    }
}

__global__ __launch_bounds__(512, 4)
void nhrep_main(const float* __restrict__ x, float* __restrict__ out,
                const unsigned short* __restrict__ wsW,
                const float* __restrict__ wsB, int npts, int nbig)
{
    __shared__ unsigned short act[96 * LDA];   // 50688 B
    __shared__ float xst[96 * 4];              // 1536 B -> 52224 B total
    const int b = blockIdx.x;
    if (b < nbig) {
        run_net<3>(x, out, wsW, wsB, act, xst, b * 96, npts, threadIdx.x);
    } else {
        run_net<1>(x, out, wsW, wsB, act, xst,
                   nbig * 96 + (b - nbig) * 32, npts, threadIdx.x);
    }
}

// ---------------------------------------------------------------------------
// Fused prepack with scale folding (proven since R4, identity k-mapping).
// Frag (mt,kk,lane,j) = scale(l,k) * W^T[mt*16+(lane&15)][kk*32+(lane>>4)*8+j]
// ---------------------------------------------------------------------------
struct PackArgs {
    const float* W[8];
    const float* b[8];
};

#define TOTAL_FRAGS 50688
#define TOTAL_BIAS  1808

__global__ void prepack_all(PackArgs args, unsigned short* __restrict__ dstW,
                            float* __restrict__ dstB)
{
    const int t = blockIdx.x * blockDim.x + threadIdx.x;
    const int FB[9]  = {0, 1024, 9216, 17408, 25600, 33792, 41984, 50176, 50688};
    const int KKs[8] = {1, 8, 8, 8, 8, 8, 8, 8};
    const int ind[8] = {3, 256, 256, 256, 256, 256, 256, 256};
    const int outd[8]= {256, 256, 256, 253, 256, 256, 256, 8};

    if (t < TOTAL_FRAGS) {
        int l = 0;
        while (t >= FB[l + 1]) ++l;
        const int f    = t - FB[l];
        const int lane = f & 63;
        const int kk   = (f >> 6) % KKs[l];
        const int mt   = f / (64 * KKs[l]);
        const int o    = mt * 16 + (lane & 15);
        const int kb   = kk * 32 + (lane >> 4) * 8;
        const float* W = args.W[l];
        const int in_d = ind[l], out_d = outd[l];

        unsigned short v[8];
#pragma unroll
        for (int j = 0; j < 8; ++j) {
            const int k = kb + j;
            float w = 0.0f;
            if (k < in_d && o < out_d) {
                float sc = 1.0f;
                if (l == 0) sc = SCALE_T2;
                else if (l == 4) sc = (k < 253) ? INV_SQRT2 : (SCALE_T2 * INV_SQRT2);
                else if (l == 7) sc = LN2_100;
                w = W[k * out_d + o] * sc;
            }
            unsigned int u = __float_as_uint(w);
            v[j] = (unsigned short)((u + 0x7FFFu + ((u >> 16) & 1u)) >> 16);
        }
        uint4 p;
        p.x = (unsigned int)v[0] | ((unsigned int)v[1] << 16);
        p.y = (unsigned int)v[2] | ((unsigned int)v[3] << 16);
        p.z = (unsigned int)v[4] | ((unsigned int)v[5] << 16);
        p.w = (unsigned int)v[6] | ((unsigned int)v[7] << 16);
        *(uint4*)(dstW + (long)t * 8) = p;
    } else if (t < TOTAL_FRAGS + TOTAL_BIAS) {
        const int u = t - TOTAL_FRAGS;
        const int l = (u < 1792) ? (u >> 8) : 7;
        const int idx = (l < 7) ? (u & 255) : (u - 1792);
        const float sc = (l < 7) ? SCALE_T2 : 1.0f;   // b7 stays in output units
        dstB[u] = (idx < outd[l]) ? args.b[l][idx] * sc : 0.0f;
    }
}

extern "C" void kernel_launch(void* const* d_in, const int* in_sizes, int n_in,
                              void* d_out, int out_size, void* d_ws, size_t ws_size,
                              hipStream_t stream)
{
    const float* x = (const float*)d_in[0];
    unsigned short* wsW = (unsigned short*)d_ws;
    float* wsB = (float*)((char*)d_ws + WSB_BYTE_OFF);

    PackArgs pa;
    for (int l = 0; l < 8; ++l) {
        pa.W[l] = (const float*)d_in[1 + 2 * l];
        pa.b[l] = (const float*)d_in[2 + 2 * l];
    }
    const int ptot = TOTAL_FRAGS + TOTAL_BIAS;
    prepack_all<<<(ptot + 255) / 256, 256, 0, stream>>>(pa, wsW, wsB);

    const int npts = in_sizes[0] / 3;            // 100000
    // Mixed grid: 96-pt blocks for the bulk, 32-pt blocks for the drain tail.
    int nbig, nsmall;
    const int tail_pts = 16384;
    if (npts > tail_pts) {
        nbig = (npts - tail_pts + 95) / 96;      // 871
        const int base_small = nbig * 96;
        nsmall = (npts - base_small + 31) / 32;  // ~512
    } else {
        nbig = 0;
        nsmall = (npts + 31) / 32;
    }
    nhrep_main<<<nbig + nsmall, 512, 0, stream>>>(x, (float*)d_out, wsW, wsB,
                                                  npts, nbig);
}

// Round 2
// 193.349 us; speedup vs baseline: 1.0080x; 1.0080x over previous
//
#include <hip/hip_runtime.h>
#include <hip/hip_bf16.h>

// ---------------------------------------------------------------------------
// NHRepNet fused forward, Round 16: kk-sliced A/B stagger (pressure-bounded).
//
// Established (R1-R15):
//  - R14 (96-pt, 2 bar/layer, phase-serial): 115us = mfma-phase ~61us
//    (LDS-pipe 92% busy) + epi-phase ~54us (VALU-bound). Overlap prize ~50us.
//  - R15 (free-form dual-acc stagger, NTG=3): SPILLED — WRITE_SIZE 3.5->30.7MB,
//    dur 126us, MfmaUtil fell. Scheduler merged full epi into full mfma phase;
//    live set blew the 128-reg cap. Mechanism wrong, goal stands.
//
// R16: stagger retained, two fixes:
//  (1) NTG=2 -> 64-pt tiles, dual acc = 32 regs (not 48); total live ~90-105.
//      A/pt rises 1.33->2KB (~+11us L2-A) — rides the under-utilized VMEM pipe.
//  (2) Manual kk-granular interleave: each kk step = {ds_read bfr, load afr ->
//      ONE epi slice (4 softplus+pack+store8B) of the other group's prev-layer
//      acc -> 4 MFMAs}. Slice index compile-time (i=kk&1, nt=kk>>1). Epi VALU
//      sits in the load-wait shadow; temps die per-slice; no bulk live merge.
//  L7 staggered too: [L7-mfma(A) || epi_B(6)]; bar; L7(B).
// Gate #1: WRITE_SIZE must return to ~3.5MB. Gate #2: MfmaUtil+VALUBusy > 95%.
// ---------------------------------------------------------------------------

using bf16x8 = __attribute__((ext_vector_type(8))) __bf16;
using f32x4  = __attribute__((ext_vector_type(4))) float;

#define LDA 264   // padded activation row stride (bf16)

#define OFFW0 0
#define OFFW1 8192
#define OFFW7 401408
#define WSB_BYTE_OFF 811008   // fp32 bias region
#define OFFB7 1792            // L0..L6 at l*256; L7 at 1792 (16 floats, padded)

#define SCALE_T2 144.26950408889634f      // 100*log2(e)
#define INV_SQRT2 0.70710678118654752f
#define LN2_100 0.0069314718055994531f    // ln2/100

__device__ __forceinline__ float fast_exp2(float x) {
#if __has_builtin(__builtin_amdgcn_exp2f)
    return __builtin_amdgcn_exp2f(x);
#else
    return exp2f(x);
#endif
}
__device__ __forceinline__ float fast_log2(float x) {
#if __has_builtin(__builtin_amdgcn_logf)
    return __builtin_amdgcn_logf(x);
#else
    return log2f(x);
#endif
}

// a2 = max(t2,0) + log2(1 + 2^-|t2|)   (t2-domain; scales folded into weights)
__device__ __forceinline__ float softplus_t2(float t2) {
    float e = fast_exp2(-fabsf(t2));
    float l = fast_log2(1.0f + e);
    return fmaxf(t2, 0.0f) + l;
}

__device__ __forceinline__ unsigned short bf16_rne(float f) {
    unsigned int u = __float_as_uint(f);
    unsigned int r = u + 0x7FFFu + ((u >> 16) & 1u);
    return (unsigned short)(r >> 16);
}

// ---------------------------------------------------------------------------
// Plain MFMA half (used for tiny layer 0 only). Wave owns ch [wave*32,+32).
// ---------------------------------------------------------------------------
template <int KK, int NTG>
__device__ __forceinline__ void mfma_group(
    const unsigned short* __restrict__ wfrag,
    const float* __restrict__ bias,
    const unsigned short* act,
    f32x4 (&acc)[2][NTG], int wave, int lane)
{
    const int quad = lane >> 4;
    const int l15  = lane & 15;

#pragma unroll
    for (int i = 0; i < 2; ++i) {
        const int chb = (wave * 2 + i) * 16 + quad * 4;
        const float4 b4 = *(const float4*)(bias + chb);
#pragma unroll
        for (int nt = 0; nt < NTG; ++nt)
            acc[i][nt] = f32x4{b4.x, b4.y, b4.z, b4.w};
    }

    const unsigned short* wbase = wfrag + (wave * 2 * KK * 64 + lane) * 8;

#pragma unroll
    for (int kk = 0; kk < KK; ++kk) {
        bf16x8 bfr[NTG];
#pragma unroll
        for (int nt = 0; nt < NTG; ++nt)
            bfr[nt] = *(const bf16x8*)(act + (nt * 16 + l15) * LDA + kk * 32 + quad * 8);
#pragma unroll
        for (int i = 0; i < 2; ++i) {
            bf16x8 afr = *(const bf16x8*)(wbase + (i * KK + kk) * 512);
#pragma unroll
            for (int nt = 0; nt < NTG; ++nt)
                acc[i][nt] = __builtin_amdgcn_mfma_f32_16x16x32_bf16(afr, bfr[nt], acc[i][nt], 0, 0, 0);
        }
    }
}

// ---------------------------------------------------------------------------
// One epilogue slice: softplus + pack + 8B store for combo (i,nt) of acc.
// splice: layer-3 raw-x fixup, only lanes with chb==252 (wave7,i=1,quad=3).
// ---------------------------------------------------------------------------
template <int I, int NT>
__device__ __forceinline__ void epi_slice(
    const f32x4& a4, unsigned short* act, const float* xst,
    bool splice, int wave, int quad, int l15)
{
    const int chb = (wave * 2 + I) * 16 + quad * 4;
    const int pt  = NT * 16 + l15;
    float vv[4];
#pragma unroll
    for (int r = 0; r < 4; ++r)
        vv[r] = softplus_t2(a4[r]);
    if (splice && chb == 252) {   // ch 253..255 <- raw x (W4 absorbs scales)
        vv[1] = xst[pt * 4 + 0];
        vv[2] = xst[pt * 4 + 1];
        vv[3] = xst[pt * 4 + 2];
    }
    __hip_bfloat162 p01 = __float22bfloat162_rn(float2{vv[0], vv[1]});
    __hip_bfloat162 p23 = __float22bfloat162_rn(float2{vv[2], vv[3]});
    uint2 pk;
    pk.x = *(unsigned int*)&p01;
    pk.y = *(unsigned int*)&p23;
    *(uint2*)(act + pt * LDA + chb) = pk;
}

// Full epilogue of a group (used where no mfma to hide under).
template <int NTG>
__device__ __forceinline__ void epi_group(
    f32x4 (&acc)[2][NTG], unsigned short* act, const float* xst,
    int wave, int lane, bool splice)
{
    const int quad = lane >> 4;
    const int l15  = lane & 15;
#pragma unroll
    for (int i = 0; i < 2; ++i)
#pragma unroll
        for (int nt = 0; nt < NTG; ++nt) {
            if (i == 0) epi_slice<0, 0>(acc[0][nt], act + nt * 16 * LDA - 0, xst + nt * 0, splice, wave, quad, l15);
            // (compile-time dispatch below instead — see note)
        }
    // NOTE: simple explicit form (kept unambiguous for the compiler):
}

// Explicit full epilogue without the template gymnastics above.
template <int NTG>
__device__ __forceinline__ void epi_group_full(
    f32x4 (&acc)[2][NTG], unsigned short* act, const float* xst,
    int wave, int lane, bool splice)
{
    const int quad = lane >> 4;
    const int l15  = lane & 15;
#pragma unroll
    for (int i = 0; i < 2; ++i) {
        const int chb = (wave * 2 + i) * 16 + quad * 4;
#pragma unroll
        for (int nt = 0; nt < NTG; ++nt) {
            const int pt = nt * 16 + l15;
            float vv[4];
#pragma unroll
            for (int r = 0; r < 4; ++r)
                vv[r] = softplus_t2(acc[i][nt][r]);
            if (splice && chb == 252) {
                vv[1] = xst[pt * 4 + 0];
                vv[2] = xst[pt * 4 + 1];
                vv[3] = xst[pt * 4 + 2];
            }
            __hip_bfloat162 p01 = __float22bfloat162_rn(float2{vv[0], vv[1]});
            __hip_bfloat162 p23 = __float22bfloat162_rn(float2{vv[2], vv[3]});
            uint2 pk;
            pk.x = *(unsigned int*)&p01;
            pk.y = *(unsigned int*)&p23;
            *(uint2*)(act + pt * LDA + chb) = pk;
        }
    }
}

// ---------------------------------------------------------------------------
// Staggered region: build accX = W.actX + b (full K-loop) while retiring accY
// (other group's previous-layer preacts) one slice per kk step. Slice VALU
// fills the ds_read/global_load wait shadow of the same kk.
// ---------------------------------------------------------------------------
template <int KK, int NTG>
__device__ __forceinline__ void stag_region(
    const unsigned short* __restrict__ wfrag,
    const float* __restrict__ bias,
    const unsigned short* __restrict__ actX,
    unsigned short* actY,
    f32x4 (&accX)[2][NTG], f32x4 (&accY)[2][NTG],
    const float* xstY, bool splice, int wave, int lane)
{
    const int quad = lane >> 4;
    const int l15  = lane & 15;

#pragma unroll
    for (int i = 0; i < 2; ++i) {
        const int chb = (wave * 2 + i) * 16 + quad * 4;
        const float4 b4 = *(const float4*)(bias + chb);
#pragma unroll
        for (int nt = 0; nt < NTG; ++nt)
            accX[i][nt] = f32x4{b4.x, b4.y, b4.z, b4.w};
    }

    const unsigned short* wbase = wfrag + (wave * 2 * KK * 64 + lane) * 8;

#pragma unroll
    for (int kk = 0; kk < KK; ++kk) {
        // loads first (ds + vmem), epi VALU in their shadow, mfma last
        bf16x8 bfr[NTG];
#pragma unroll
        for (int nt = 0; nt < NTG; ++nt)
            bfr[nt] = *(const bf16x8*)(actX + (nt * 16 + l15) * LDA + kk * 32 + quad * 8);
        bf16x8 afr0 = *(const bf16x8*)(wbase + kk * 512);
        bf16x8 afr1 = *(const bf16x8*)(wbase + (KK + kk) * 512);

        if (kk < 2 * NTG) {   // compile-time: one retired slice of group Y
            constexpr int c = 0;  (void)c;
            const int i  = kk & 1;       // compile-time under full unroll
            const int nt = kk >> 1;
            const int chb = (wave * 2 + i) * 16 + quad * 4;
            const int pt  = nt * 16 + l15;
            float vv[4];
#pragma unroll
            for (int r = 0; r < 4; ++r)
                vv[r] = softplus_t2(accY[i][nt][r]);
            if (splice && chb == 252) {
                vv[1] = xstY[pt * 4 + 0];
                vv[2] = xstY[pt * 4 + 1];
                vv[3] = xstY[pt * 4 + 2];
            }
            __hip_bfloat162 p01 = __float22bfloat162_rn(float2{vv[0], vv[1]});
            __hip_bfloat162 p23 = __float22bfloat162_rn(float2{vv[2], vv[3]});
            uint2 pk;
            pk.x = *(unsigned int*)&p01;
            pk.y = *(unsigned int*)&p23;
            *(uint2*)(actY + pt * LDA + chb) = pk;
        }

#pragma unroll
        for (int nt = 0; nt < NTG; ++nt)
            accX[0][nt] = __builtin_amdgcn_mfma_f32_16x16x32_bf16(afr0, bfr[nt], accX[0][nt], 0, 0, 0);
#pragma unroll
        for (int nt = 0; nt < NTG; ++nt)
            accX[1][nt] = __builtin_amdgcn_mfma_f32_16x16x32_bf16(afr1, bfr[nt], accX[1][nt], 0, 0, 0);
    }
}

// ---------------------------------------------------------------------------
// Layer 7 (256->8) for one group: waves [0,NTG) handle 16 pts each at rows
// row0 = goff + wave*16; reduce + CSG + store.
// ---------------------------------------------------------------------------
__device__ __forceinline__ void l7_part(
    const unsigned short* act, const unsigned short* __restrict__ w7,
    const float* __restrict__ wsB, float* __restrict__ out,
    int row0, int ptg0, int npts, int lane)
{
    const int quad = lane >> 4, l15 = lane & 15;
    const float4 b4 = *(const float4*)(wsB + OFFB7 + quad * 4);  // quads>=2: zeros
    f32x4 acc = f32x4{b4.x, b4.y, b4.z, b4.w};
#pragma unroll
    for (int kk = 0; kk < 8; ++kk) {
        bf16x8 bfr = *(const bf16x8*)(act + (row0 + l15) * LDA + kk * 32 + quad * 8);
        bf16x8 afr = *(const bf16x8*)(w7 + (kk * 64 + lane) * 8);
        acc = __builtin_amdgcn_mfma_f32_16x16x32_bf16(afr, bfr, acc, 0, 0, 0);
    }
    // quad0 lanes hold ch0-3, quad1 ch4-7 for pt = row0+l15
    float u0 = __shfl(acc[0], l15 + 16);
    float u1 = __shfl(acc[1], l15 + 16);
    float u2 = __shfl(acc[2], l15 + 16);
    float u3 = __shfl(acc[3], l15 + 16);
    if (quad == 0) {
        const int ptg = ptg0 + l15;
        if (ptg < npts) {
            const float v0 = acc[0], v1 = acc[1], v2 = acc[2], v3 = acc[3];
            const float v4 = u0, v5 = u1, v6 = u2, v7 = u3;
            const float m23   = fminf(v2, v3);
            const float m67   = fmaxf(v6, v7);
            const float m4567 = fminf(fminf(v4, v5), m67);
            const float h     = fmaxf(fmaxf(v0, v1), fmaxf(m23, m4567));
            float* o = out + (long)ptg * 9;
            o[0] = h;
            o[1] = v0; o[2] = v1; o[3] = v2; o[4] = v3;
            o[5] = v4; o[6] = v5; o[7] = v6; o[8] = v7;
        }
    }
}

// ---------------------------------------------------------------------------
// Full network for one tile of 2*NTG*16 points (NTG=2 -> 64, NTG=1 -> 32),
// two staggered in-place groups A (rows 0..NTG*16) and B (rest). Schedule:
//   stage; bar
//   mfma_A(0); bar
//   mfma_B(0); epi_A(0); bar
//   l=1..6:  stag[mfma_A(l) + slices of accB(l-1)]; bar
//            stag[mfma_B(l) + slices of accA(l)];   bar
//   [L7(A) || epi_B(6)]; bar;  L7(B)
// ---------------------------------------------------------------------------
template <int NTG>
__device__ __forceinline__ void run_net(
    const float* __restrict__ x, float* __restrict__ out,
    const unsigned short* __restrict__ wsW, const float* __restrict__ wsB,
    unsigned short* act, float* xst,
    int base_pt, int npts, int tid)
{
    const int wave = tid >> 6, lane = tid & 63;

    // stage x into act channels 0..2, zero-pad to 32 (K-pad for layer 0)
    for (int i = tid; i < 2 * NTG * 16 * 32; i += 512) {
        const int pt = i >> 5, ch = i & 31;
        const int ptg = base_pt + pt;
        float v = 0.0f;
        if (ch < 3 && ptg < npts) v = x[ptg * 3 + ch];
        act[pt * LDA + ch] = bf16_rne(v);
        if (ch < 4) xst[pt * 4 + ch] = (ch < 3) ? v : 0.0f;
    }
    __syncthreads();

    unsigned short* actA = act;
    unsigned short* actB = act + NTG * 16 * LDA;
    const float* xstA = xst;
    const float* xstB = xst + NTG * 16 * 4;

    f32x4 accA[2][NTG], accB[2][NTG];

    // layer 0 (KK=1, tiny): A alone, then B with serial epi_A
    mfma_group<1, NTG>(wsW + OFFW0, wsB, actA, accA, wave, lane);
    __syncthreads();
    mfma_group<1, NTG>(wsW + OFFW0, wsB, actB, accB, wave, lane);
    epi_group_full<NTG>(accA, actA, xstA, wave, lane, false);
    __syncthreads();

    // layers 1..6, two staggered regions each
#pragma unroll 1
    for (int l = 1; l <= 6; ++l) {
        const unsigned short* Wl = wsW + OFFW1 + (l - 1) * 65536;
        const float* bl = wsB + l * 256;

        // mfma_A(l) + retire accB(l-1)  (splice when l-1 == 3)
        stag_region<8, NTG>(Wl, bl, actA, actB, accA, accB, xstB, l == 4, wave, lane);
        __syncthreads();

        // mfma_B(l) + retire accA(l)    (splice when l == 3)
        stag_region<8, NTG>(Wl, bl, actB, actA, accB, accA, xstA, l == 3, wave, lane);
        __syncthreads();
    }

    // [L7(A) || epi_B(6)]: actA finalized last region; epi writes actB only.
    if (wave < NTG)
        l7_part(act, wsW + OFFW7, wsB, out, wave * 16, base_pt + wave * 16, npts, lane);
    epi_group_full<NTG>(accB, actB, xstB, wave, lane, false);
    __syncthreads();

    // L7(B)
    if (wave < NTG)
        l7_part(act, wsW + OFFW7, wsB, out,
                NTG * 16 + wave * 16, base_pt + NTG * 16 + wave * 16, npts, lane);
}

__global__ __launch_bounds__(512, 4)
void nhrep_main(const float* __restrict__ x, float* __restrict__ out,
                const unsigned short* __restrict__ wsW,
                const float* __restrict__ wsB, int npts, int nbig)
{
    __shared__ unsigned short act[64 * LDA];   // 33792 B
    __shared__ float xst[64 * 4];              // 1024 B -> 34816 B total
    const int b = blockIdx.x;
    if (b < nbig) {
        run_net<2>(x, out, wsW, wsB, act, xst, b * 64, npts, threadIdx.x);
    } else {
        run_net<1>(x, out, wsW, wsB, act, xst,
                   nbig * 64 + (b - nbig) * 32, npts, threadIdx.x);
    }
}

// ---------------------------------------------------------------------------
// Fused prepack with scale folding (proven since R4, identity k-mapping).
// Frag (mt,kk,lane,j) = scale(l,k) * W^T[mt*16+(lane&15)][kk*32+(lane>>4)*8+j]
// ---------------------------------------------------------------------------
struct PackArgs {
    const float* W[8];
    const float* b[8];
};

#define TOTAL_FRAGS 50688
#define TOTAL_BIAS  1808

__global__ void prepack_all(PackArgs args, unsigned short* __restrict__ dstW,
                            float* __restrict__ dstB)
{
    const int t = blockIdx.x * blockDim.x + threadIdx.x;
    const int FB[9]  = {0, 1024, 9216, 17408, 25600, 33792, 41984, 50176, 50688};
    const int KKs[8] = {1, 8, 8, 8, 8, 8, 8, 8};
    const int ind[8] = {3, 256, 256, 256, 256, 256, 256, 256};
    const int outd[8]= {256, 256, 256, 253, 256, 256, 256, 8};

    if (t < TOTAL_FRAGS) {
        int l = 0;
        while (t >= FB[l + 1]) ++l;
        const int f    = t - FB[l];
        const int lane = f & 63;
        const int kk   = (f >> 6) % KKs[l];
        const int mt   = f / (64 * KKs[l]);
        const int o    = mt * 16 + (lane & 15);
        const int kb   = kk * 32 + (lane >> 4) * 8;
        const float* W = args.W[l];
        const int in_d = ind[l], out_d = outd[l];

        unsigned short v[8];
#pragma unroll
        for (int j = 0; j < 8; ++j) {
            const int k = kb + j;
            float w = 0.0f;
            if (k < in_d && o < out_d) {
                float sc = 1.0f;
                if (l == 0) sc = SCALE_T2;
                else if (l == 4) sc = (k < 253) ? INV_SQRT2 : (SCALE_T2 * INV_SQRT2);
                else if (l == 7) sc = LN2_100;
                w = W[k * out_d + o] * sc;
            }
            unsigned int u = __float_as_uint(w);
            v[j] = (unsigned short)((u + 0x7FFFu + ((u >> 16) & 1u)) >> 16);
        }
        uint4 p;
        p.x = (unsigned int)v[0] | ((unsigned int)v[1] << 16);
        p.y = (unsigned int)v[2] | ((unsigned int)v[3] << 16);
        p.z = (unsigned int)v[4] | ((unsigned int)v[5] << 16);
        p.w = (unsigned int)v[6] | ((unsigned int)v[7] << 16);
        *(uint4*)(dstW + (long)t * 8) = p;
    } else if (t < TOTAL_FRAGS + TOTAL_BIAS) {
        const int u = t - TOTAL_FRAGS;
        const int l = (u < 1792) ? (u >> 8) : 7;
        const int idx = (l < 7) ? (u & 255) : (u - 1792);
        const float sc = (l < 7) ? SCALE_T2 : 1.0f;   // b7 stays in output units
        dstB[u] = (idx < outd[l]) ? args.b[l][idx] * sc : 0.0f;
    }
}

extern "C" void kernel_launch(void* const* d_in, const int* in_sizes, int n_in,
                              void* d_out, int out_size, void* d_ws, size_t ws_size,
                              hipStream_t stream)
{
    const float* x = (const float*)d_in[0];
    unsigned short* wsW = (unsigned short*)d_ws;
    float* wsB = (float*)((char*)d_ws + WSB_BYTE_OFF);

    PackArgs pa;
    for (int l = 0; l < 8; ++l) {
        pa.W[l] = (const float*)d_in[1 + 2 * l];
        pa.b[l] = (const float*)d_in[2 + 2 * l];
    }
    const int ptot = TOTAL_FRAGS + TOTAL_BIAS;
    prepack_all<<<(ptot + 255) / 256, 256, 0, stream>>>(pa, wsW, wsB);

    const int npts = in_sizes[0] / 3;            // 100000
    // Mixed grid: 64-pt blocks for the bulk, 32-pt blocks for the drain tail.
    int nbig, nsmall;
    const int tail_pts = 16384;
    if (npts > tail_pts) {
        nbig = (npts - tail_pts + 63) / 64;      // ~1307
        const int base_small = nbig * 64;
        nsmall = (npts - base_small + 31) / 32;  // ~511
    } else {
        nbig = 0;
        nsmall = (npts + 31) / 32;
    }
    nhrep_main<<<nbig + nsmall, 512, 0, stream>>>(x, (float*)d_out, wsW, wsB,
                                                  npts, nbig);
}

// Round 3
// 179.931 us; speedup vs baseline: 1.0832x; 1.0746x over previous
//
#include <hip/hip_runtime.h>
#include <hip/hip_bf16.h>

// ---------------------------------------------------------------------------
// NHRepNet fused forward, Round 17: 96-pt kk-sliced stagger + weight prefetch.
//
// Established (R1-R16):
//  - R14 (96-pt, phase-serial): 115us = mfma-phase ~61us + epi-phase ~54us.
//    mfma phase == LDS-B throughput floor (3GB @ ~85B/cyc/CU ~= 57us): the
//    phase is NOT latency-bound; only pipe overlap or Gch reduction helps.
//  - R15 (free-form dual-acc): spilled (WRITE 30.7MB). Slice discipline (R16)
//    holds pressure: WRITE back to 3.5MB at VGPR=64.
//  - R16 (kk-sliced stagger, 64-pt): dur 120.4 = 115 + A-traffic penalty of
//    1.5x blocks; interleave effect indistinguishable from zero — confounded.
//
// R17 = clean A/B vs R14: identical geometry (96-pt tiles, 871+512 grid,
// 52224B LDS, 2 bar/layer, same A-traffic), ONLY deltas:
//  (1) kk-granular epi interleave (NTG=3: 6 slices over kk=0..5), epi VALU
//      sits between bfr ds_reads and MFMAs = LDS-latency shadow.
//  (2) depth-1 explicit afr (weight) prefetch: kk+1 loads issue before kk's
//      MFMAs; at VGPR=64 the compiler provably didn't pipeline these.
// Regs: 48 acc + ~75 arch ~= 123 <= 128-tier, 2 blk/CU. Gate #1: WRITE_SIZE
// ~3.5MB (spill). Gate #2: MfmaUtil+VALUBusy > 95% (overlap). Null -> R18
// pivots to Gch=4/Gpt=2 (halve LDS-B floor).
// ---------------------------------------------------------------------------

using bf16x8 = __attribute__((ext_vector_type(8))) __bf16;
using f32x4  = __attribute__((ext_vector_type(4))) float;

#define LDA 264   // padded activation row stride (bf16)

#define OFFW0 0
#define OFFW1 8192
#define OFFW7 401408
#define WSB_BYTE_OFF 811008   // fp32 bias region
#define OFFB7 1792            // L0..L6 at l*256; L7 at 1792 (16 floats, padded)

#define SCALE_T2 144.26950408889634f      // 100*log2(e)
#define INV_SQRT2 0.70710678118654752f
#define LN2_100 0.0069314718055994531f    // ln2/100

__device__ __forceinline__ float fast_exp2(float x) {
#if __has_builtin(__builtin_amdgcn_exp2f)
    return __builtin_amdgcn_exp2f(x);
#else
    return exp2f(x);
#endif
}
__device__ __forceinline__ float fast_log2(float x) {
#if __has_builtin(__builtin_amdgcn_logf)
    return __builtin_amdgcn_logf(x);
#else
    return log2f(x);
#endif
}

// a2 = max(t2,0) + log2(1 + 2^-|t2|)   (t2-domain; scales folded into weights)
__device__ __forceinline__ float softplus_t2(float t2) {
    float e = fast_exp2(-fabsf(t2));
    float l = fast_log2(1.0f + e);
    return fmaxf(t2, 0.0f) + l;
}

__device__ __forceinline__ unsigned short bf16_rne(float f) {
    unsigned int u = __float_as_uint(f);
    unsigned int r = u + 0x7FFFu + ((u >> 16) & 1u);
    return (unsigned short)(r >> 16);
}

// ---------------------------------------------------------------------------
// Plain MFMA half (used for tiny layer 0 only). Wave owns ch [wave*32,+32).
// ---------------------------------------------------------------------------
template <int KK, int NTG>
__device__ __forceinline__ void mfma_group(
    const unsigned short* __restrict__ wfrag,
    const float* __restrict__ bias,
    const unsigned short* act,
    f32x4 (&acc)[2][NTG], int wave, int lane)
{
    const int quad = lane >> 4;
    const int l15  = lane & 15;

#pragma unroll
    for (int i = 0; i < 2; ++i) {
        const int chb = (wave * 2 + i) * 16 + quad * 4;
        const float4 b4 = *(const float4*)(bias + chb);
#pragma unroll
        for (int nt = 0; nt < NTG; ++nt)
            acc[i][nt] = f32x4{b4.x, b4.y, b4.z, b4.w};
    }

    const unsigned short* wbase = wfrag + (wave * 2 * KK * 64 + lane) * 8;

#pragma unroll
    for (int kk = 0; kk < KK; ++kk) {
        bf16x8 bfr[NTG];
#pragma unroll
        for (int nt = 0; nt < NTG; ++nt)
            bfr[nt] = *(const bf16x8*)(act + (nt * 16 + l15) * LDA + kk * 32 + quad * 8);
#pragma unroll
        for (int i = 0; i < 2; ++i) {
            bf16x8 afr = *(const bf16x8*)(wbase + (i * KK + kk) * 512);
#pragma unroll
            for (int nt = 0; nt < NTG; ++nt)
                acc[i][nt] = __builtin_amdgcn_mfma_f32_16x16x32_bf16(afr, bfr[nt], acc[i][nt], 0, 0, 0);
        }
    }
}

// Full epilogue of a group (used where no mfma to hide under).
template <int NTG>
__device__ __forceinline__ void epi_group_full(
    f32x4 (&acc)[2][NTG], unsigned short* act, const float* xst,
    int wave, int lane, bool splice)
{
    const int quad = lane >> 4;
    const int l15  = lane & 15;
#pragma unroll
    for (int i = 0; i < 2; ++i) {
        const int chb = (wave * 2 + i) * 16 + quad * 4;
#pragma unroll
        for (int nt = 0; nt < NTG; ++nt) {
            const int pt = nt * 16 + l15;
            float vv[4];
#pragma unroll
            for (int r = 0; r < 4; ++r)
                vv[r] = softplus_t2(acc[i][nt][r]);
            if (splice && chb == 252) {
                vv[1] = xst[pt * 4 + 0];
                vv[2] = xst[pt * 4 + 1];
                vv[3] = xst[pt * 4 + 2];
            }
            __hip_bfloat162 p01 = __float22bfloat162_rn(float2{vv[0], vv[1]});
            __hip_bfloat162 p23 = __float22bfloat162_rn(float2{vv[2], vv[3]});
            uint2 pk;
            pk.x = *(unsigned int*)&p01;
            pk.y = *(unsigned int*)&p23;
            *(uint2*)(act + pt * LDA + chb) = pk;
        }
    }
}

// ---------------------------------------------------------------------------
// Staggered region: build accX = W.actX + b while retiring accY (other
// group's previous-layer preacts) one slice per kk step. Slice VALU sits
// between bfr ds_reads and MFMAs (LDS-latency shadow); afr weight loads are
// explicitly prefetched one kk ahead (hidden under previous kk's MFMAs).
// ---------------------------------------------------------------------------
template <int KK, int NTG>
__device__ __forceinline__ void stag_region(
    const unsigned short* __restrict__ wfrag,
    const float* __restrict__ bias,
    const unsigned short* __restrict__ actX,
    unsigned short* actY,
    f32x4 (&accX)[2][NTG], f32x4 (&accY)[2][NTG],
    const float* xstY, bool splice, int wave, int lane)
{
    const int quad = lane >> 4;
    const int l15  = lane & 15;

#pragma unroll
    for (int i = 0; i < 2; ++i) {
        const int chb = (wave * 2 + i) * 16 + quad * 4;
        const float4 b4 = *(const float4*)(bias + chb);
#pragma unroll
        for (int nt = 0; nt < NTG; ++nt)
            accX[i][nt] = f32x4{b4.x, b4.y, b4.z, b4.w};
    }

    const unsigned short* wbase = wfrag + (wave * 2 * KK * 64 + lane) * 8;

    // depth-1 weight prefetch (L2 latency rides under previous kk's MFMAs)
    bf16x8 afr0 = *(const bf16x8*)(wbase);
    bf16x8 afr1 = *(const bf16x8*)(wbase + KK * 512);

#pragma unroll
    for (int kk = 0; kk < KK; ++kk) {
        const bf16x8 a0 = afr0, a1 = afr1;
        if (kk + 1 < KK) {
            afr0 = *(const bf16x8*)(wbase + (kk + 1) * 512);
            afr1 = *(const bf16x8*)(wbase + (KK + kk + 1) * 512);
        }

        bf16x8 bfr[NTG];
#pragma unroll
        for (int nt = 0; nt < NTG; ++nt)
            bfr[nt] = *(const bf16x8*)(actX + (nt * 16 + l15) * LDA + kk * 32 + quad * 8);

        if (kk < 2 * NTG) {   // one retired slice of group Y (compile-time idx)
            const int i  = kk & 1;       // constant under full unroll
            const int nt = kk >> 1;
            const int chb = (wave * 2 + i) * 16 + quad * 4;
            const int pt  = nt * 16 + l15;
            float vv[4];
#pragma unroll
            for (int r = 0; r < 4; ++r)
                vv[r] = softplus_t2(accY[i][nt][r]);
            if (splice && chb == 252) {   // ch 253..255 <- raw x
                vv[1] = xstY[pt * 4 + 0];
                vv[2] = xstY[pt * 4 + 1];
                vv[3] = xstY[pt * 4 + 2];
            }
            __hip_bfloat162 p01 = __float22bfloat162_rn(float2{vv[0], vv[1]});
            __hip_bfloat162 p23 = __float22bfloat162_rn(float2{vv[2], vv[3]});
            uint2 pk;
            pk.x = *(unsigned int*)&p01;
            pk.y = *(unsigned int*)&p23;
            *(uint2*)(actY + pt * LDA + chb) = pk;
        }

#pragma unroll
        for (int nt = 0; nt < NTG; ++nt)
            accX[0][nt] = __builtin_amdgcn_mfma_f32_16x16x32_bf16(a0, bfr[nt], accX[0][nt], 0, 0, 0);
#pragma unroll
        for (int nt = 0; nt < NTG; ++nt)
            accX[1][nt] = __builtin_amdgcn_mfma_f32_16x16x32_bf16(a1, bfr[nt], accX[1][nt], 0, 0, 0);
    }
}

// ---------------------------------------------------------------------------
// Layer 7 (256->8) for one group: waves [0,NTG) handle 16 pts each at rows
// row0; reduce + CSG + store.
// ---------------------------------------------------------------------------
__device__ __forceinline__ void l7_part(
    const unsigned short* act, const unsigned short* __restrict__ w7,
    const float* __restrict__ wsB, float* __restrict__ out,
    int row0, int ptg0, int npts, int lane)
{
    const int quad = lane >> 4, l15 = lane & 15;
    const float4 b4 = *(const float4*)(wsB + OFFB7 + quad * 4);  // quads>=2: zeros
    f32x4 acc = f32x4{b4.x, b4.y, b4.z, b4.w};
#pragma unroll
    for (int kk = 0; kk < 8; ++kk) {
        bf16x8 bfr = *(const bf16x8*)(act + (row0 + l15) * LDA + kk * 32 + quad * 8);
        bf16x8 afr = *(const bf16x8*)(w7 + (kk * 64 + lane) * 8);
        acc = __builtin_amdgcn_mfma_f32_16x16x32_bf16(afr, bfr, acc, 0, 0, 0);
    }
    // quad0 lanes hold ch0-3, quad1 ch4-7 for pt = row0+l15
    float u0 = __shfl(acc[0], l15 + 16);
    float u1 = __shfl(acc[1], l15 + 16);
    float u2 = __shfl(acc[2], l15 + 16);
    float u3 = __shfl(acc[3], l15 + 16);
    if (quad == 0) {
        const int ptg = ptg0 + l15;
        if (ptg < npts) {
            const float v0 = acc[0], v1 = acc[1], v2 = acc[2], v3 = acc[3];
            const float v4 = u0, v5 = u1, v6 = u2, v7 = u3;
            const float m23   = fminf(v2, v3);
            const float m67   = fmaxf(v6, v7);
            const float m4567 = fminf(fminf(v4, v5), m67);
            const float h     = fmaxf(fmaxf(v0, v1), fmaxf(m23, m4567));
            float* o = out + (long)ptg * 9;
            o[0] = h;
            o[1] = v0; o[2] = v1; o[3] = v2; o[4] = v3;
            o[5] = v4; o[6] = v5; o[7] = v6; o[8] = v7;
        }
    }
}

// ---------------------------------------------------------------------------
// Full network for one tile of 2*NTG*16 points (NTG=3 -> 96, NTG=1 -> 32),
// two staggered in-place groups A (rows 0..NTG*16) and B (rest). Schedule:
//   stage; bar
//   mfma_A(0); bar
//   mfma_B(0); epi_A(0); bar
//   l=1..6:  stag[mfma_A(l) + slices of accB(l-1)]; bar
//            stag[mfma_B(l) + slices of accA(l)];   bar
//   [L7(A) || epi_B(6)]; bar;  L7(B)
// ---------------------------------------------------------------------------
template <int NTG>
__device__ __forceinline__ void run_net(
    const float* __restrict__ x, float* __restrict__ out,
    const unsigned short* __restrict__ wsW, const float* __restrict__ wsB,
    unsigned short* act, float* xst,
    int base_pt, int npts, int tid)
{
    const int wave = tid >> 6, lane = tid & 63;

    // stage x into act channels 0..2, zero-pad to 32 (K-pad for layer 0)
    for (int i = tid; i < 2 * NTG * 16 * 32; i += 512) {
        const int pt = i >> 5, ch = i & 31;
        const int ptg = base_pt + pt;
        float v = 0.0f;
        if (ch < 3 && ptg < npts) v = x[ptg * 3 + ch];
        act[pt * LDA + ch] = bf16_rne(v);
        if (ch < 4) xst[pt * 4 + ch] = (ch < 3) ? v : 0.0f;
    }
    __syncthreads();

    unsigned short* actA = act;
    unsigned short* actB = act + NTG * 16 * LDA;
    const float* xstA = xst;
    const float* xstB = xst + NTG * 16 * 4;

    f32x4 accA[2][NTG], accB[2][NTG];

    // layer 0 (KK=1, tiny): A alone, then B with serial epi_A
    mfma_group<1, NTG>(wsW + OFFW0, wsB, actA, accA, wave, lane);
    __syncthreads();
    mfma_group<1, NTG>(wsW + OFFW0, wsB, actB, accB, wave, lane);
    epi_group_full<NTG>(accA, actA, xstA, wave, lane, false);
    __syncthreads();

    // layers 1..6, two staggered regions each
#pragma unroll 1
    for (int l = 1; l <= 6; ++l) {
        const unsigned short* Wl = wsW + OFFW1 + (l - 1) * 65536;
        const float* bl = wsB + l * 256;

        // mfma_A(l) + retire accB(l-1)  (splice when l-1 == 3)
        stag_region<8, NTG>(Wl, bl, actA, actB, accA, accB, xstB, l == 4, wave, lane);
        __syncthreads();

        // mfma_B(l) + retire accA(l)    (splice when l == 3)
        stag_region<8, NTG>(Wl, bl, actB, actA, accB, accA, xstA, l == 3, wave, lane);
        __syncthreads();
    }

    // [L7(A) || epi_B(6)]: actA finalized last region; epi writes actB only.
    if (wave < NTG)
        l7_part(act, wsW + OFFW7, wsB, out, wave * 16, base_pt + wave * 16, npts, lane);
    epi_group_full<NTG>(accB, actB, xstB, wave, lane, false);
    __syncthreads();

    // L7(B)
    if (wave < NTG)
        l7_part(act, wsW + OFFW7, wsB, out,
                NTG * 16 + wave * 16, base_pt + NTG * 16 + wave * 16, npts, lane);
}

__global__ __launch_bounds__(512, 4)
void nhrep_main(const float* __restrict__ x, float* __restrict__ out,
                const unsigned short* __restrict__ wsW,
                const float* __restrict__ wsB, int npts, int nbig)
{
    __shared__ unsigned short act[96 * LDA];   // 50688 B
    __shared__ float xst[96 * 4];              // 1536 B -> 52224 B total
    const int b = blockIdx.x;
    if (b < nbig) {
        run_net<3>(x, out, wsW, wsB, act, xst, b * 96, npts, threadIdx.x);
    } else {
        run_net<1>(x, out, wsW, wsB, act, xst,
                   nbig * 96 + (b - nbig) * 32, npts, threadIdx.x);
    }
}

// ---------------------------------------------------------------------------
// Fused prepack with scale folding (proven since R4, identity k-mapping).
// Frag (mt,kk,lane,j) = scale(l,k) * W^T[mt*16+(lane&15)][kk*32+(lane>>4)*8+j]
// ---------------------------------------------------------------------------
struct PackArgs {
    const float* W[8];
    const float* b[8];
};

#define TOTAL_FRAGS 50688
#define TOTAL_BIAS  1808

__global__ void prepack_all(PackArgs args, unsigned short* __restrict__ dstW,
                            float* __restrict__ dstB)
{
    const int t = blockIdx.x * blockDim.x + threadIdx.x;
    const int FB[9]  = {0, 1024, 9216, 17408, 25600, 33792, 41984, 50176, 50688};
    const int KKs[8] = {1, 8, 8, 8, 8, 8, 8, 8};
    const int ind[8] = {3, 256, 256, 256, 256, 256, 256, 256};
    const int outd[8]= {256, 256, 256, 253, 256, 256, 256, 8};

    if (t < TOTAL_FRAGS) {
        int l = 0;
        while (t >= FB[l + 1]) ++l;
        const int f    = t - FB[l];
        const int lane = f & 63;
        const int kk   = (f >> 6) % KKs[l];
        const int mt   = f / (64 * KKs[l]);
        const int o    = mt * 16 + (lane & 15);
        const int kb   = kk * 32 + (lane >> 4) * 8;
        const float* W = args.W[l];
        const int in_d = ind[l], out_d = outd[l];

        unsigned short v[8];
#pragma unroll
        for (int j = 0; j < 8; ++j) {
            const int k = kb + j;
            float w = 0.0f;
            if (k < in_d && o < out_d) {
                float sc = 1.0f;
                if (l == 0) sc = SCALE_T2;
                else if (l == 4) sc = (k < 253) ? INV_SQRT2 : (SCALE_T2 * INV_SQRT2);
                else if (l == 7) sc = LN2_100;
                w = W[k * out_d + o] * sc;
            }
            unsigned int u = __float_as_uint(w);
            v[j] = (unsigned short)((u + 0x7FFFu + ((u >> 16) & 1u)) >> 16);
        }
        uint4 p;
        p.x = (unsigned int)v[0] | ((unsigned int)v[1] << 16);
        p.y = (unsigned int)v[2] | ((unsigned int)v[3] << 16);
        p.z = (unsigned int)v[4] | ((unsigned int)v[5] << 16);
        p.w = (unsigned int)v[6] | ((unsigned int)v[7] << 16);
        *(uint4*)(dstW + (long)t * 8) = p;
    } else if (t < TOTAL_FRAGS + TOTAL_BIAS) {
        const int u = t - TOTAL_FRAGS;
        const int l = (u < 1792) ? (u >> 8) : 7;
        const int idx = (l < 7) ? (u & 255) : (u - 1792);
        const float sc = (l < 7) ? SCALE_T2 : 1.0f;   // b7 stays in output units
        dstB[u] = (idx < outd[l]) ? args.b[l][idx] * sc : 0.0f;
    }
}

extern "C" void kernel_launch(void* const* d_in, const int* in_sizes, int n_in,
                              void* d_out, int out_size, void* d_ws, size_t ws_size,
                              hipStream_t stream)
{
    const float* x = (const float*)d_in[0];
    unsigned short* wsW = (unsigned short*)d_ws;
    float* wsB = (float*)((char*)d_ws + WSB_BYTE_OFF);

    PackArgs pa;
    for (int l = 0; l < 8; ++l) {
        pa.W[l] = (const float*)d_in[1 + 2 * l];
        pa.b[l] = (const float*)d_in[2 + 2 * l];
    }
    const int ptot = TOTAL_FRAGS + TOTAL_BIAS;
    prepack_all<<<(ptot + 255) / 256, 256, 0, stream>>>(pa, wsW, wsB);

    const int npts = in_sizes[0] / 3;            // 100000
    // Mixed grid: 96-pt blocks for the bulk, 32-pt blocks for the drain tail.
    int nbig, nsmall;
    const int tail_pts = 16384;
    if (npts > tail_pts) {
        nbig = (npts - tail_pts + 95) / 96;      // 871
        const int base_small = nbig * 96;
        nsmall = (npts - base_small + 31) / 32;  // 512
    } else {
        nbig = 0;
        nsmall = (npts + 31) / 32;
    }
    nhrep_main<<<nbig + nsmall, 512, 0, stream>>>(x, (float*)d_out, wsW, wsB,
                                                  npts, nbig);
}